// Round 1
// baseline (574.793 us; speedup 1.0000x reference)
//
#include <hip/hip_runtime.h>

// Problem constants (LoRAExpert): T tokens, E experts, IN/OUT dims, A adapters, R rank
#define T_TOK 16384
#define NEXP 8
#define DIN 1024
#define DOUT 1024
#define NADP 8
#define RANK 16
#define MAXTILES 135   // 128 full tiles + up to E-1 boundary remainders

typedef float f32x4 __attribute__((ext_vector_type(4)));
typedef __bf16 bf16x8 __attribute__((ext_vector_type(8)));

typedef __attribute__((address_space(3))) void lds_void;
typedef __attribute__((address_space(1))) void g_void;

// fp32 -> bf16 bit pattern, round-to-nearest-even
static __device__ __forceinline__ unsigned short f2bf(float f) {
    union { float f; unsigned u; } c; c.f = f;
    unsigned r = c.u + 0x7FFFu + ((c.u >> 16) & 1u);
    return (unsigned short)(r >> 16);
}

// ---------------- K1a: convert x (T x IN fp32) -> bf16, zero-pad 128 extra rows ----------------
__global__ __launch_bounds__(256) void k_convert_x(const float* __restrict__ x,
                                                   unsigned short* __restrict__ xb) {
    size_t i = ((size_t)blockIdx.x * 256 + threadIdx.x) * 4;
    ushort4 u;
    if (i < (size_t)T_TOK * DIN) {
        float4 v = *(const float4*)(x + i);
        u.x = f2bf(v.x); u.y = f2bf(v.y); u.z = f2bf(v.z); u.w = f2bf(v.w);
    } else {
        u.x = 0; u.y = 0; u.z = 0; u.w = 0;
    }
    *(ushort4*)(xb + i) = u;
}

// ---------------- K1b: convert+transpose weight [E][IN][OUT] fp32 -> [E][OUT][IN] bf16 --------
__global__ __launch_bounds__(256) void k_convert_wt(const float* __restrict__ W,
                                                    unsigned short* __restrict__ Wt) {
    __shared__ __attribute__((aligned(16))) unsigned short tile[64][80]; // pad: 160B row stride, 16B-aligned rows
    int e = blockIdx.z;
    int k0 = blockIdx.x * 64, n0 = blockIdx.y * 64;
    const float* We = W + (size_t)e * DIN * DOUT;
    unsigned short* Wte = Wt + (size_t)e * DIN * DOUT;
    int t = threadIdx.x;
    int kr = t >> 2;            // 0..63 (k row)
    int nc = (t & 3) * 16;      // 16 floats per thread
#pragma unroll
    for (int j = 0; j < 4; j++) {
        float4 v = *(const float4*)(We + (size_t)(k0 + kr) * DOUT + n0 + nc + j * 4);
        tile[nc + j * 4 + 0][kr] = f2bf(v.x);
        tile[nc + j * 4 + 1][kr] = f2bf(v.y);
        tile[nc + j * 4 + 2][kr] = f2bf(v.z);
        tile[nc + j * 4 + 3][kr] = f2bf(v.w);
    }
    __syncthreads();
    int n = t >> 2;             // 0..63 (out-feature row of Wt)
    int kk = (t & 3) * 16;      // 16 bf16 per thread
    uint4 v0 = *(const uint4*)&tile[n][kk];
    uint4 v1 = *(const uint4*)&tile[n][kk + 8];
    *(uint4*)(Wte + (size_t)(n0 + n) * DIN + k0 + kk) = v0;
    *(uint4*)(Wte + (size_t)(n0 + n) * DIN + k0 + kk + 8) = v1;
}

// ---------------- K2: grouped-GEMM tile schedule (each tile = one expert) ----------------------
__global__ void k_schedule(const int* __restrict__ gs, int* __restrict__ sched) {
    if (threadIdx.x != 0 || blockIdx.x != 0) return;
    int off = 0, tc = 0;
    for (int e = 0; e < NEXP; e++) {
        int sz = gs[e];
        for (int m = 0; m < sz; m += 128) {
            sched[tc * 4 + 0] = e;
            sched[tc * 4 + 1] = off + m;
            sched[tc * 4 + 2] = (sz - m) < 128 ? (sz - m) : 128;
            sched[tc * 4 + 3] = 0;
            tc++;
        }
        off += sz;
    }
    for (; tc < MAXTILES; tc++) {
        sched[tc * 4 + 0] = 0; sched[tc * 4 + 1] = 0; sched[tc * 4 + 2] = 0; sched[tc * 4 + 3] = 0;
    }
}

// ---------------- K3: base grouped GEMM, bf16 MFMA, m97-style 128x128x32 ----------------------
__global__ __launch_bounds__(256) void k_gemm(const unsigned short* __restrict__ xb,
                                              const unsigned short* __restrict__ wt,
                                              const int* __restrict__ sched,
                                              float* __restrict__ out) {
    __shared__ __attribute__((aligned(16))) unsigned short As[128 * 32];
    __shared__ __attribute__((aligned(16))) unsigned short Bs[128 * 32];
    int e     = sched[blockIdx.x * 4 + 0];
    int m0    = sched[blockIdx.x * 4 + 1];
    int valid = sched[blockIdx.x * 4 + 2];
    if (valid == 0) return;
    int n0 = blockIdx.y * 128;

    int t = threadIdx.x;
    int lane = t & 63;
    int wave = t >> 6;
    int wm = wave >> 1, wn = wave & 1;   // 2x2 wave grid, 64x64 per wave
    int ln = lane & 15, q = lane >> 4;

    const unsigned short* wte = wt + (size_t)e * DIN * DOUT;

    f32x4 acc[4][4];
#pragma unroll
    for (int i = 0; i < 4; i++)
#pragma unroll
        for (int j = 0; j < 4; j++) acc[i][j] = (f32x4){0.f, 0.f, 0.f, 0.f};

    int c0 = t, c1 = t + 256; // 16B chunk ids: chunk c covers row c>>2, k-subblock (c&3)*8

    for (int k0 = 0; k0 < DIN; k0 += 32) {
        __syncthreads();
        {
            const unsigned short* ga0 = xb + (size_t)(m0 + (c0 >> 2)) * DIN + k0 + (c0 & 3) * 8;
            const unsigned short* ga1 = xb + (size_t)(m0 + (c1 >> 2)) * DIN + k0 + (c1 & 3) * 8;
            __builtin_amdgcn_global_load_lds((const g_void*)ga0, (lds_void*)((char*)As + wave * 1024), 16, 0, 0);
            __builtin_amdgcn_global_load_lds((const g_void*)ga1, (lds_void*)((char*)As + 4096 + wave * 1024), 16, 0, 0);
            const unsigned short* gb0 = wte + (size_t)(n0 + (c0 >> 2)) * DIN + k0 + (c0 & 3) * 8;
            const unsigned short* gb1 = wte + (size_t)(n0 + (c1 >> 2)) * DIN + k0 + (c1 & 3) * 8;
            __builtin_amdgcn_global_load_lds((const g_void*)gb0, (lds_void*)((char*)Bs + wave * 1024), 16, 0, 0);
            __builtin_amdgcn_global_load_lds((const g_void*)gb1, (lds_void*)((char*)Bs + 4096 + wave * 1024), 16, 0, 0);
        }
        __syncthreads();
        bf16x8 af[4], bf[4];
#pragma unroll
        for (int mi = 0; mi < 4; mi++)
            af[mi] = *(const bf16x8*)((const char*)As + ((wm * 64 + mi * 16 + ln) * 64 + q * 16));
#pragma unroll
        for (int ni = 0; ni < 4; ni++)
            bf[ni] = *(const bf16x8*)((const char*)Bs + ((wn * 64 + ni * 16 + ln) * 64 + q * 16));
#pragma unroll
        for (int mi = 0; mi < 4; mi++)
#pragma unroll
            for (int ni = 0; ni < 4; ni++)
                acc[mi][ni] = __builtin_amdgcn_mfma_f32_16x16x32_bf16(af[mi], bf[ni], acc[mi][ni], 0, 0, 0);
    }

    // epilogue: C/D layout col=lane&15, row=q*4+reg
#pragma unroll
    for (int mi = 0; mi < 4; mi++) {
#pragma unroll
        for (int r = 0; r < 4; r++) {
            int row_l = wm * 64 + mi * 16 + q * 4 + r;
            if (row_l < valid) {
                float* orow = out + (size_t)(m0 + row_l) * DOUT + n0 + wn * 64 + ln;
#pragma unroll
                for (int ni = 0; ni < 4; ni++)
                    orow[ni * 16] = acc[mi][ni][r];
            }
        }
    }
}

// ---------------- K4: LoRA in fp32, one wave per token, RMW-add into out ----------------------
__global__ __launch_bounds__(256) void k_lora(const float* __restrict__ x,
                                              const int* __restrict__ gs,
                                              const int* __restrict__ aidx,
                                              const float* __restrict__ lA,
                                              const float* __restrict__ lB,
                                              const float* __restrict__ scal,
                                              float* __restrict__ out) {
    int wave = threadIdx.x >> 6;
    int lane = threadIdx.x & 63;
    int tok = blockIdx.x * 4 + wave;

    // expert id from group sizes (tokens sorted by expert)
    int e = 0, accs = 0;
#pragma unroll
    for (int i = 0; i < NEXP; i++) { accs += gs[i]; if (tok >= accs) e = i + 1; }
    int a = aidx[tok];

    const float* Amat = lA + (size_t)(a * NEXP + e) * DIN * RANK; // [k][r]
    const float* xrow = x + (size_t)tok * DIN;

    float inter[RANK];
#pragma unroll
    for (int r = 0; r < RANK; r++) inter[r] = 0.f;

#pragma unroll 4
    for (int i = 0; i < DIN / 64; i++) {
        int k = lane + i * 64;
        float xv = xrow[k];
        const float4* ar = (const float4*)(Amat + (size_t)k * RANK);
        float4 a0 = ar[0], a1 = ar[1], a2 = ar[2], a3 = ar[3];
        inter[0]  += xv * a0.x; inter[1]  += xv * a0.y; inter[2]  += xv * a0.z; inter[3]  += xv * a0.w;
        inter[4]  += xv * a1.x; inter[5]  += xv * a1.y; inter[6]  += xv * a1.z; inter[7]  += xv * a1.w;
        inter[8]  += xv * a2.x; inter[9]  += xv * a2.y; inter[10] += xv * a2.z; inter[11] += xv * a2.w;
        inter[12] += xv * a3.x; inter[13] += xv * a3.y; inter[14] += xv * a3.z; inter[15] += xv * a3.w;
    }
    // butterfly reduce each of the 16 partials across the wave
#pragma unroll
    for (int off = 32; off > 0; off >>= 1)
#pragma unroll
        for (int r = 0; r < RANK; r++)
            inter[r] += __shfl_xor(inter[r], off, 64);

    float s = scal[a];
    const float* Bmat = lB + (size_t)(a * NEXP + e) * RANK * DOUT; // [r][n]
    float* orow = out + (size_t)tok * DOUT;
#pragma unroll
    for (int c = 0; c < DOUT / 64; c++) {
        int j = lane + c * 64;
        float v = 0.f;
#pragma unroll
        for (int r = 0; r < RANK; r++)
            v += inter[r] * Bmat[r * DOUT + j];
        orow[j] += s * v;
    }
}

extern "C" void kernel_launch(void* const* d_in, const int* in_sizes, int n_in,
                              void* d_out, int out_size, void* d_ws, size_t ws_size,
                              hipStream_t stream) {
    (void)in_sizes; (void)n_in; (void)out_size; (void)ws_size;
    const float* x    = (const float*)d_in[0];
    const int*   gs   = (const int*)d_in[1];
    const int*   aidx = (const int*)d_in[2];
    const float* W    = (const float*)d_in[3];
    const float* lA   = (const float*)d_in[4];
    const float* lB   = (const float*)d_in[5];
    const float* scal = (const float*)d_in[6];
    float* out = (float*)d_out;

    // ws layout
    char* ws = (char*)d_ws;
    unsigned short* xb = (unsigned short*)ws;                        // (T+128)*1024*2 = 33,816,576 B
    unsigned short* wt = (unsigned short*)(ws + 33816576);           // 8*1024*1024*2  = 16,777,216 B
    int* sched = (int*)(ws + 33816576 + 16777216);                   // 135*4*4 B

    k_convert_x<<<16512, 256, 0, stream>>>(x, xb);                   // (T+128)*1024/4/256
    k_convert_wt<<<dim3(16, 16, 8), 256, 0, stream>>>(W, wt);
    k_schedule<<<1, 64, 0, stream>>>(gs, sched);
    k_gemm<<<dim3(MAXTILES, 8), 256, 0, stream>>>(xb, wt, sched, out);
    k_lora<<<T_TOK / 4, 256, 0, stream>>>(x, gs, aidx, lA, lB, scal, out);
}

// Round 2
// 358.735 us; speedup vs baseline: 1.6023x; 1.6023x over previous
//
#include <hip/hip_runtime.h>

// Problem constants (LoRAExpert)
#define T_TOK 16384
#define NEXP 8
#define DIN 1024
#define DOUT 1024
#define NADP 8
#define RANK 16
#define NGRP 64        // E*A groups
#define MAXTILES 135   // base gemm: 128 full + up to E-1 remainders
#define MAXT2 192      // lora gemm: 128 full + up to NGRP remainders

typedef float f32x4 __attribute__((ext_vector_type(4)));
typedef __bf16 bf16x8 __attribute__((ext_vector_type(8)));

typedef __attribute__((address_space(3))) void lds_void;
typedef __attribute__((address_space(1))) void g_void;

static __device__ __forceinline__ unsigned short f2bf(float f) {
    union { float f; unsigned u; } c; c.f = f;
    unsigned r = c.u + 0x7FFFu + ((c.u >> 16) & 1u);
    return (unsigned short)(r >> 16);
}

// ---------------- convert x (T x IN fp32) -> bf16, zero-pad 128 extra rows ----------------
__global__ __launch_bounds__(256) void k_convert_x(const float* __restrict__ x,
                                                   unsigned short* __restrict__ xb) {
    size_t i = ((size_t)blockIdx.x * 256 + threadIdx.x) * 4;
    ushort4 u;
    if (i < (size_t)T_TOK * DIN) {
        float4 v = *(const float4*)(x + i);
        u.x = f2bf(v.x); u.y = f2bf(v.y); u.z = f2bf(v.z); u.w = f2bf(v.w);
    } else {
        u.x = 0; u.y = 0; u.z = 0; u.w = 0;
    }
    *(ushort4*)(xb + i) = u;
}

// ---------------- convert+transpose weight [E][IN][OUT] fp32 -> [E][OUT][IN] bf16 --------
__global__ __launch_bounds__(256) void k_convert_wt(const float* __restrict__ W,
                                                    unsigned short* __restrict__ Wt) {
    __shared__ __attribute__((aligned(16))) unsigned short tile[64][80];
    int e = blockIdx.z;
    int k0 = blockIdx.x * 64, n0 = blockIdx.y * 64;
    const float* We = W + (size_t)e * DIN * DOUT;
    unsigned short* Wte = Wt + (size_t)e * DIN * DOUT;
    int t = threadIdx.x;
    int kr = t >> 2;
    int nc = (t & 3) * 16;
#pragma unroll
    for (int j = 0; j < 4; j++) {
        float4 v = *(const float4*)(We + (size_t)(k0 + kr) * DOUT + n0 + nc + j * 4);
        tile[nc + j * 4 + 0][kr] = f2bf(v.x);
        tile[nc + j * 4 + 1][kr] = f2bf(v.y);
        tile[nc + j * 4 + 2][kr] = f2bf(v.z);
        tile[nc + j * 4 + 3][kr] = f2bf(v.w);
    }
    __syncthreads();
    int n = t >> 2;
    int kk = (t & 3) * 16;
    uint4 v0 = *(const uint4*)&tile[n][kk];
    uint4 v1 = *(const uint4*)&tile[n][kk + 8];
    *(uint4*)(Wte + (size_t)(n0 + n) * DIN + k0 + kk) = v0;
    *(uint4*)(Wte + (size_t)(n0 + n) * DIN + k0 + kk + 8) = v1;
}

// ------------- convert+transpose lora_A [A][E][K][R] fp32 -> Agt [g=e*8+a][R][K] bf16 -----
__global__ __launch_bounds__(256) void k_convert_lora(const float* __restrict__ lA,
                                                      unsigned short* __restrict__ Agt) {
    __shared__ __attribute__((aligned(16))) unsigned short sm[16][1032];
    int g = blockIdx.x, a = g & 7, e = g >> 3;
    const float* src = lA + (size_t)(a * NEXP + e) * DIN * RANK;
    int t = threadIdx.x;
#pragma unroll
    for (int it = 0; it < 4; it++) {
        int k = it * 256 + t;
        const float4* p = (const float4*)(src + (size_t)k * RANK);
        float4 v0 = p[0], v1 = p[1], v2 = p[2], v3 = p[3];
        sm[0][k] = f2bf(v0.x);  sm[1][k] = f2bf(v0.y);  sm[2][k] = f2bf(v0.z);  sm[3][k] = f2bf(v0.w);
        sm[4][k] = f2bf(v1.x);  sm[5][k] = f2bf(v1.y);  sm[6][k] = f2bf(v1.z);  sm[7][k] = f2bf(v1.w);
        sm[8][k] = f2bf(v2.x);  sm[9][k] = f2bf(v2.y);  sm[10][k] = f2bf(v2.z); sm[11][k] = f2bf(v2.w);
        sm[12][k] = f2bf(v3.x); sm[13][k] = f2bf(v3.y); sm[14][k] = f2bf(v3.z); sm[15][k] = f2bf(v3.w);
    }
    __syncthreads();
    unsigned short* dst = Agt + (size_t)g * RANK * DIN;
    int r = t >> 4, ks = (t & 15) * 64;
#pragma unroll
    for (int j = 0; j < 8; j++)
        *(uint4*)(dst + r * DIN + ks + j * 8) = *(const uint4*)&sm[r][ks + j * 8];
}

// ---------------- routing: zero hist ----------------
__global__ void k_zero(int* __restrict__ hist) {
    hist[threadIdx.x] = 0;
}

// ---------------- routing: per-token group id + histogram ----------------
__global__ __launch_bounds__(256) void k_route(const int* __restrict__ gs,
                                               const int* __restrict__ aidx,
                                               int* __restrict__ gid,
                                               int* __restrict__ hist) {
    int tok = blockIdx.x * 256 + threadIdx.x;
    int e = 0, acc = 0;
#pragma unroll
    for (int i = 0; i < NEXP; i++) { acc += gs[i]; if (tok >= acc) e = i + 1; }
    int g = e * NADP + aidx[tok];
    gid[tok] = g;
    atomicAdd(&hist[g], 1);
}

// ---------------- routing: scan + tile schedule for lora passes ----------------
__global__ void k_scan(const int* __restrict__ hist, int* __restrict__ cursor,
                       int* __restrict__ sched2, int* __restrict__ perm) {
    if (threadIdx.x == 0) {
        int off = 0, tc = 0;
        for (int g = 0; g < NGRP; g++) {
            cursor[g] = off;
            int sz = hist[g];
            for (int m = 0; m < sz; m += 128) {
                sched2[tc * 4 + 0] = g;
                sched2[tc * 4 + 1] = off + m;
                sched2[tc * 4 + 2] = (sz - m) < 128 ? (sz - m) : 128;
                sched2[tc * 4 + 3] = 0;
                tc++;
            }
            off += sz;
        }
        for (; tc < MAXT2; tc++) {
            sched2[tc * 4 + 0] = 0; sched2[tc * 4 + 1] = 0;
            sched2[tc * 4 + 2] = 0; sched2[tc * 4 + 3] = 0;
        }
    }
    // pad perm so pass1 tile overrun gathers the zero row of xb
    int t = threadIdx.x;
    perm[T_TOK + t] = T_TOK;
    perm[T_TOK + 64 + t] = T_TOK;
}

// ---------------- routing: scatter tokens into group-sorted order ----------------
__global__ __launch_bounds__(256) void k_scatter(const int* __restrict__ gid,
                                                 int* __restrict__ cursor,
                                                 int* __restrict__ perm) {
    int tok = blockIdx.x * 256 + threadIdx.x;
    int pos = atomicAdd(&cursor[gid[tok]], 1);
    perm[pos] = tok;
}

// ---------------- base gemm tile schedule ----------------
__global__ void k_schedule(const int* __restrict__ gs, int* __restrict__ sched) {
    if (threadIdx.x != 0 || blockIdx.x != 0) return;
    int off = 0, tc = 0;
    for (int e = 0; e < NEXP; e++) {
        int sz = gs[e];
        for (int m = 0; m < sz; m += 128) {
            sched[tc * 4 + 0] = e;
            sched[tc * 4 + 1] = off + m;
            sched[tc * 4 + 2] = (sz - m) < 128 ? (sz - m) : 128;
            sched[tc * 4 + 3] = 0;
            tc++;
        }
        off += sz;
    }
    for (; tc < MAXTILES; tc++) {
        sched[tc * 4 + 0] = 0; sched[tc * 4 + 1] = 0; sched[tc * 4 + 2] = 0; sched[tc * 4 + 3] = 0;
    }
}

// ---------------- base grouped GEMM, bf16 MFMA, 128x128x32 ----------------
__global__ __launch_bounds__(256) void k_gemm(const unsigned short* __restrict__ xb,
                                              const unsigned short* __restrict__ wt,
                                              const int* __restrict__ sched,
                                              float* __restrict__ out) {
    __shared__ __attribute__((aligned(16))) unsigned short As[128 * 32];
    __shared__ __attribute__((aligned(16))) unsigned short Bs[128 * 32];
    int e     = sched[blockIdx.x * 4 + 0];
    int m0    = sched[blockIdx.x * 4 + 1];
    int valid = sched[blockIdx.x * 4 + 2];
    if (valid == 0) return;
    int n0 = blockIdx.y * 128;

    int t = threadIdx.x;
    int lane = t & 63;
    int wave = t >> 6;
    int wm = wave >> 1, wn = wave & 1;
    int ln = lane & 15, q = lane >> 4;

    const unsigned short* wte = wt + (size_t)e * DIN * DOUT;

    f32x4 acc[4][4];
#pragma unroll
    for (int i = 0; i < 4; i++)
#pragma unroll
        for (int j = 0; j < 4; j++) acc[i][j] = (f32x4){0.f, 0.f, 0.f, 0.f};

    int c0 = t, c1 = t + 256;

    for (int k0 = 0; k0 < DIN; k0 += 32) {
        __syncthreads();
        {
            const unsigned short* ga0 = xb + (size_t)(m0 + (c0 >> 2)) * DIN + k0 + (c0 & 3) * 8;
            const unsigned short* ga1 = xb + (size_t)(m0 + (c1 >> 2)) * DIN + k0 + (c1 & 3) * 8;
            __builtin_amdgcn_global_load_lds((const g_void*)ga0, (lds_void*)((char*)As + wave * 1024), 16, 0, 0);
            __builtin_amdgcn_global_load_lds((const g_void*)ga1, (lds_void*)((char*)As + 4096 + wave * 1024), 16, 0, 0);
            const unsigned short* gb0 = wte + (size_t)(n0 + (c0 >> 2)) * DIN + k0 + (c0 & 3) * 8;
            const unsigned short* gb1 = wte + (size_t)(n0 + (c1 >> 2)) * DIN + k0 + (c1 & 3) * 8;
            __builtin_amdgcn_global_load_lds((const g_void*)gb0, (lds_void*)((char*)Bs + wave * 1024), 16, 0, 0);
            __builtin_amdgcn_global_load_lds((const g_void*)gb1, (lds_void*)((char*)Bs + 4096 + wave * 1024), 16, 0, 0);
        }
        __syncthreads();
        bf16x8 af[4], bfr[4];
#pragma unroll
        for (int mi = 0; mi < 4; mi++)
            af[mi] = *(const bf16x8*)((const char*)As + ((wm * 64 + mi * 16 + ln) * 64 + q * 16));
#pragma unroll
        for (int ni = 0; ni < 4; ni++)
            bfr[ni] = *(const bf16x8*)((const char*)Bs + ((wn * 64 + ni * 16 + ln) * 64 + q * 16));
#pragma unroll
        for (int mi = 0; mi < 4; mi++)
#pragma unroll
            for (int ni = 0; ni < 4; ni++)
                acc[mi][ni] = __builtin_amdgcn_mfma_f32_16x16x32_bf16(af[mi], bfr[ni], acc[mi][ni], 0, 0, 0);
    }

#pragma unroll
    for (int mi = 0; mi < 4; mi++) {
#pragma unroll
        for (int r = 0; r < 4; r++) {
            int row_l = wm * 64 + mi * 16 + q * 4 + r;
            if (row_l < valid) {
                float* orow = out + (size_t)(m0 + row_l) * DOUT + n0 + wn * 64 + ln;
#pragma unroll
                for (int ni = 0; ni < 4; ni++)
                    orow[ni * 16] = acc[mi][ni][r];
            }
        }
    }
}

// ---------------- lora pass1: inter = gather(xb, perm) @ Agt[g]^T, MFMA 128x16 tiles ------
__global__ __launch_bounds__(256) void k_pass1(const unsigned short* __restrict__ xb,
                                               const unsigned short* __restrict__ Agt,
                                               const int* __restrict__ sched2,
                                               const int* __restrict__ perm,
                                               float* __restrict__ inter) {
    __shared__ __attribute__((aligned(16))) unsigned short As[128 * 32];
    int g     = sched2[blockIdx.x * 4 + 0];
    int m0    = sched2[blockIdx.x * 4 + 1];
    int valid = sched2[blockIdx.x * 4 + 2];
    if (valid == 0) return;

    int t = threadIdx.x;
    int lane = t & 63, w = t >> 6;
    int ln = lane & 15, q = lane >> 4;

    const unsigned short* Ag = Agt + (size_t)g * RANK * DIN;
    int prow0 = perm[m0 + (t >> 2)];
    int prow1 = perm[m0 + 64 + (t >> 2)];

    f32x4 acc[2];
    acc[0] = (f32x4){0.f, 0.f, 0.f, 0.f};
    acc[1] = (f32x4){0.f, 0.f, 0.f, 0.f};

    for (int k0 = 0; k0 < DIN; k0 += 32) {
        __syncthreads();
        {
            const unsigned short* ga0 = xb + (size_t)prow0 * DIN + k0 + (t & 3) * 8;
            const unsigned short* ga1 = xb + (size_t)prow1 * DIN + k0 + (t & 3) * 8;
            __builtin_amdgcn_global_load_lds((const g_void*)ga0, (lds_void*)((char*)As + w * 1024), 16, 0, 0);
            __builtin_amdgcn_global_load_lds((const g_void*)ga1, (lds_void*)((char*)As + 4096 + w * 1024), 16, 0, 0);
        }
        __syncthreads();
        bf16x8 bfr = *(const bf16x8*)(Ag + ln * DIN + k0 + q * 8);
#pragma unroll
        for (int mi = 0; mi < 2; mi++) {
            bf16x8 af = *(const bf16x8*)((const char*)As + ((w * 32 + mi * 16 + ln) * 64 + q * 16));
            acc[mi] = __builtin_amdgcn_mfma_f32_16x16x32_bf16(af, bfr, acc[mi], 0, 0, 0);
        }
    }
#pragma unroll
    for (int mi = 0; mi < 2; mi++) {
#pragma unroll
        for (int r = 0; r < 4; r++) {
            int row = w * 32 + mi * 16 + q * 4 + r;
            if (row < valid)
                inter[(size_t)(m0 + row) * RANK + ln] = acc[mi][r];
        }
    }
}

// ---------------- lora pass2: out[perm[t]] += s * inter[t] @ lB[g], B tile in LDS ---------
__global__ __launch_bounds__(256) void k_pass2(const float* __restrict__ inter,
                                               const int* __restrict__ sched2,
                                               const int* __restrict__ perm,
                                               const int* __restrict__ aidx,
                                               const float* __restrict__ lB,
                                               const float* __restrict__ scal,
                                               float* __restrict__ out) {
    __shared__ float Bsm[RANK * 256];   // 16 KB
    __shared__ float ism[128 * RANK];   // 8 KB
    __shared__ float ssm[128];
    __shared__ int   ptm[128];
    int g     = sched2[blockIdx.x * 4 + 0];
    int m0    = sched2[blockIdx.x * 4 + 1];
    int valid = sched2[blockIdx.x * 4 + 2];
    if (valid == 0) return;
    int n0 = blockIdx.y * 256;
    int a = g & 7, e = g >> 3;
    int t = threadIdx.x;

    // stage B chunk: [16][256] fp32
    {
        const float* Bsrc = lB + ((size_t)(a * NEXP + e) * RANK + (t >> 4)) * DOUT + n0 + (t & 15) * 16;
        float* Bdst = &Bsm[(t >> 4) * 256 + (t & 15) * 16];
#pragma unroll
        for (int j = 0; j < 4; j++)
            *(float4*)(Bdst + j * 4) = *(const float4*)(Bsrc + j * 4);
    }
    // stage inter rows + perm + scale
    {
        int tok = t >> 1, half = t & 1;
        int p = (tok < valid) ? perm[m0 + tok] : 0;
        if (half == 0) {
            ptm[tok] = p;
            ssm[tok] = (tok < valid) ? scal[aidx[p]] : 0.f;
        }
        int srow = (tok < valid) ? (m0 + tok) : m0;
        const float* ip = inter + (size_t)srow * RANK + half * 8;
        *(float4*)&ism[tok * RANK + half * 8] = *(const float4*)ip;
        *(float4*)&ism[tok * RANK + half * 8 + 4] = *(const float4*)(ip + 4);
    }
    __syncthreads();

    int lane = t & 63, w = t >> 6;
#pragma unroll 1
    for (int tk = 0; tk < 32; tk++) {
        int tok = w * 32 + tk;
        if (tok >= valid) continue;
        float s = ssm[tok];
        const float* ir = &ism[tok * RANK];
        float* orow = out + (size_t)ptm[tok] * DOUT + n0 + lane;
#pragma unroll
        for (int c = 0; c < 4; c++) {
            const float* bcol = &Bsm[lane + c * 64];
            float v = 0.f;
#pragma unroll
            for (int r = 0; r < RANK; r++)
                v += ir[r] * bcol[r * 256];
            orow[c * 64] += s * v;
        }
    }
}

extern "C" void kernel_launch(void* const* d_in, const int* in_sizes, int n_in,
                              void* d_out, int out_size, void* d_ws, size_t ws_size,
                              hipStream_t stream) {
    (void)in_sizes; (void)n_in; (void)out_size; (void)ws_size;
    const float* x    = (const float*)d_in[0];
    const int*   gs   = (const int*)d_in[1];
    const int*   aidx = (const int*)d_in[2];
    const float* W    = (const float*)d_in[3];
    const float* lA   = (const float*)d_in[4];
    const float* lB   = (const float*)d_in[5];
    const float* scal = (const float*)d_in[6];
    float* out = (float*)d_out;

    // ws layout (all 16B-aligned)
    char* ws = (char*)d_ws;
    unsigned short* xb   = (unsigned short*)ws;                     size_t o = 33816576; // (T+128)*1024*2
    unsigned short* wt   = (unsigned short*)(ws + o);               o += 16777216;       // E*IN*OUT*2
    unsigned short* Agt  = (unsigned short*)(ws + o);               o += 2097152;        // 64*16*1024*2
    float*          inter= (float*)(ws + o);                        o += 1048576;        // T*16*4
    int*            sched= (int*)(ws + o);                          o += 2176;           // 135*16
    int*            sched2=(int*)(ws + o);                          o += 3072;           // 192*16
    int*            gid  = (int*)(ws + o);                          o += 65536;          // T*4
    int*            perm = (int*)(ws + o);                          o += 66048;          // (T+128)*4
    int*            hist = (int*)(ws + o);                          o += 256;
    int*            cursor=(int*)(ws + o);                          o += 256;

    k_convert_x<<<16512, 256, 0, stream>>>(x, xb);
    k_convert_wt<<<dim3(16, 16, 8), 256, 0, stream>>>(W, wt);
    k_convert_lora<<<64, 256, 0, stream>>>(lA, Agt);
    k_zero<<<1, 64, 0, stream>>>(hist);
    k_route<<<64, 256, 0, stream>>>(gs, aidx, gid, hist);
    k_scan<<<1, 64, 0, stream>>>(hist, cursor, sched2, perm);
    k_scatter<<<64, 256, 0, stream>>>(gid, cursor, perm);
    k_schedule<<<1, 64, 0, stream>>>(gs, sched);
    k_gemm<<<dim3(MAXTILES, 8), 256, 0, stream>>>(xb, wt, sched, out);
    k_pass1<<<MAXT2, 256, 0, stream>>>(xb, Agt, sched2, perm, inter);
    k_pass2<<<dim3(MAXT2, 4), 256, 0, stream>>>(inter, sched2, perm, aidx, lB, scal, out);
}

// Round 3
// 318.755 us; speedup vs baseline: 1.8032x; 1.1254x over previous
//
#include <hip/hip_runtime.h>

// Problem constants (LoRAExpert)
#define T_TOK 16384
#define NEXP 8
#define DIN 1024
#define DOUT 1024
#define NADP 8
#define RANK 16
#define NGRP 64        // E*A groups
#define MAXTILES 135   // base gemm: 128 full + up to E-1 remainders (128-row tiles)
#define TILE2 64       // lora tiles: 64 rows
#define MAXT2 320      // 256 full + up to NGRP remainders

typedef float f32x4 __attribute__((ext_vector_type(4)));
typedef __bf16 bf16x8 __attribute__((ext_vector_type(8)));

typedef __attribute__((address_space(3))) void lds_void;
typedef __attribute__((address_space(1))) void g_void;

static __device__ __forceinline__ unsigned short f2bf(float f) {
    union { float f; unsigned u; } c; c.f = f;
    unsigned r = c.u + 0x7FFFu + ((c.u >> 16) & 1u);
    return (unsigned short)(r >> 16);
}

// ================= fused converts: x -> bf16 | W -> Wt bf16 | lora_A -> Agt bf16 =========
// block ranges: [0,16512) convert_x ; [16512,18560) convert_wt ; [18560,18624) convert_lora
#define NBX 16512
#define NBW 2048
__global__ __launch_bounds__(256) void k_convert_all(const float* __restrict__ x,
                                                     const float* __restrict__ W,
                                                     const float* __restrict__ lA,
                                                     unsigned short* __restrict__ xb,
                                                     unsigned short* __restrict__ Wt,
                                                     unsigned short* __restrict__ Agt) {
    __shared__ __attribute__((aligned(16))) unsigned short lds_u[16 * 1032]; // 33 KB union
    int b = blockIdx.x;
    int t = threadIdx.x;
    if (b < NBX) {
        // ---- convert x, zero-pad 128 extra rows ----
        size_t i = ((size_t)b * 256 + t) * 4;
        ushort4 u;
        if (i < (size_t)T_TOK * DIN) {
            float4 v = *(const float4*)(x + i);
            u.x = f2bf(v.x); u.y = f2bf(v.y); u.z = f2bf(v.z); u.w = f2bf(v.w);
        } else {
            u.x = 0; u.y = 0; u.z = 0; u.w = 0;
        }
        *(ushort4*)(xb + i) = u;
    } else if (b < NBX + NBW) {
        // ---- convert+transpose W [E][IN][OUT] -> [E][OUT][IN] ----
        int idx = b - NBX;
        int e = idx >> 8;
        int k0 = ((idx >> 4) & 15) * 64, n0 = (idx & 15) * 64;
        const float* We = W + (size_t)e * DIN * DOUT;
        unsigned short* Wte = Wt + (size_t)e * DIN * DOUT;
        int kr = t >> 2;
        int nc = (t & 3) * 16;
#pragma unroll
        for (int j = 0; j < 4; j++) {
            float4 v = *(const float4*)(We + (size_t)(k0 + kr) * DOUT + n0 + nc + j * 4);
            lds_u[(nc + j * 4 + 0) * 80 + kr] = f2bf(v.x);
            lds_u[(nc + j * 4 + 1) * 80 + kr] = f2bf(v.y);
            lds_u[(nc + j * 4 + 2) * 80 + kr] = f2bf(v.z);
            lds_u[(nc + j * 4 + 3) * 80 + kr] = f2bf(v.w);
        }
        __syncthreads();
        int n = t >> 2;
        int kk = (t & 3) * 16;
        uint4 v0 = *(const uint4*)&lds_u[n * 80 + kk];
        uint4 v1 = *(const uint4*)&lds_u[n * 80 + kk + 8];
        *(uint4*)(Wte + (size_t)(n0 + n) * DIN + k0 + kk) = v0;
        *(uint4*)(Wte + (size_t)(n0 + n) * DIN + k0 + kk + 8) = v1;
    } else {
        // ---- convert+transpose lora_A [A][E][K][R] -> Agt [g=e*8+a][R][K] ----
        int g = b - (NBX + NBW);
        int a = g & 7, e = g >> 3;
        const float* src = lA + (size_t)(a * NEXP + e) * DIN * RANK;
#pragma unroll
        for (int it = 0; it < 4; it++) {
            int k = it * 256 + t;
            const float4* p = (const float4*)(src + (size_t)k * RANK);
            float4 v0 = p[0], v1 = p[1], v2 = p[2], v3 = p[3];
            lds_u[0 * 1032 + k] = f2bf(v0.x);  lds_u[1 * 1032 + k] = f2bf(v0.y);
            lds_u[2 * 1032 + k] = f2bf(v0.z);  lds_u[3 * 1032 + k] = f2bf(v0.w);
            lds_u[4 * 1032 + k] = f2bf(v1.x);  lds_u[5 * 1032 + k] = f2bf(v1.y);
            lds_u[6 * 1032 + k] = f2bf(v1.z);  lds_u[7 * 1032 + k] = f2bf(v1.w);
            lds_u[8 * 1032 + k] = f2bf(v2.x);  lds_u[9 * 1032 + k] = f2bf(v2.y);
            lds_u[10 * 1032 + k] = f2bf(v2.z); lds_u[11 * 1032 + k] = f2bf(v2.w);
            lds_u[12 * 1032 + k] = f2bf(v3.x); lds_u[13 * 1032 + k] = f2bf(v3.y);
            lds_u[14 * 1032 + k] = f2bf(v3.z); lds_u[15 * 1032 + k] = f2bf(v3.w);
        }
        __syncthreads();
        unsigned short* dst = Agt + (size_t)g * RANK * DIN;
        int r = t >> 4, ks = (t & 15) * 64;
#pragma unroll
        for (int j = 0; j < 8; j++)
            *(uint4*)(dst + r * DIN + ks + j * 8) = *(const uint4*)&lds_u[r * 1032 + ks + j * 8];
    }
}

// ================= fused routing: hist + scan + schedules + scatter (one block) ==========
__global__ __launch_bounds__(1024) void k_route_all(const int* __restrict__ gs,
                                                    const int* __restrict__ aidx,
                                                    int* __restrict__ gid,
                                                    int* __restrict__ perm,
                                                    int* __restrict__ sched,
                                                    int* __restrict__ sched2) {
    __shared__ int hist[NGRP];
    __shared__ int cursor[NGRP];
    __shared__ int ebase[NEXP + 1];
    int t = threadIdx.x;
    if (t < NGRP) hist[t] = 0;
    if (t == 0) {
        int acc = 0;
        for (int i = 0; i < NEXP; i++) { ebase[i] = acc; acc += gs[i]; }
        ebase[NEXP] = acc;
    }
    __syncthreads();
    // phase 1: group id + LDS histogram
    for (int i = 0; i < T_TOK / 1024; i++) {
        int tok = i * 1024 + t;
        int e = 0;
#pragma unroll
        for (int j = 1; j < NEXP; j++) e += (tok >= ebase[j]);
        int g = e * NADP + aidx[tok];
        gid[tok] = g;
        atomicAdd(&hist[g], 1);
    }
    if (t < 128) perm[T_TOK + t] = T_TOK;  // pad: overruns gather zero row of xb
    __syncthreads();
    // phase 2: serial scans on two separate waves
    if (t == 0) {
        int off = 0, tc = 0;
        for (int g = 0; g < NGRP; g++) {
            cursor[g] = off;
            int sz = hist[g];
            for (int m = 0; m < sz; m += TILE2) {
                sched2[tc * 4 + 0] = g;
                sched2[tc * 4 + 1] = off + m;
                sched2[tc * 4 + 2] = (sz - m) < TILE2 ? (sz - m) : TILE2;
                sched2[tc * 4 + 3] = 0;
                tc++;
            }
            off += sz;
        }
        for (; tc < MAXT2; tc++) {
            sched2[tc * 4 + 0] = 0; sched2[tc * 4 + 1] = 0;
            sched2[tc * 4 + 2] = 0; sched2[tc * 4 + 3] = 0;
        }
    } else if (t == 64) {
        int off = 0, tc = 0;
        for (int e = 0; e < NEXP; e++) {
            int sz = ebase[e + 1] - ebase[e];
            for (int m = 0; m < sz; m += 128) {
                sched[tc * 4 + 0] = e;
                sched[tc * 4 + 1] = off + m;
                sched[tc * 4 + 2] = (sz - m) < 128 ? (sz - m) : 128;
                sched[tc * 4 + 3] = 0;
                tc++;
            }
            off += sz;
        }
        for (; tc < MAXTILES; tc++) {
            sched[tc * 4 + 0] = 0; sched[tc * 4 + 1] = 0;
            sched[tc * 4 + 2] = 0; sched[tc * 4 + 3] = 0;
        }
    }
    __syncthreads();
    // phase 3: scatter into group-sorted order (order within group irrelevant)
    for (int i = 0; i < T_TOK / 1024; i++) {
        int tok = i * 1024 + t;
        int pos = atomicAdd(&cursor[gid[tok]], 1);
        perm[pos] = tok;
    }
}

// ================= base grouped GEMM, bf16 MFMA, 128x128x32 ==============================
// grid = dim3(8, MAXTILES): n0 fastest so consecutive blocks share the A tile (L2/L3 hits)
__global__ __launch_bounds__(256) void k_gemm(const unsigned short* __restrict__ xb,
                                              const unsigned short* __restrict__ wt,
                                              const int* __restrict__ sched,
                                              float* __restrict__ out) {
    __shared__ __attribute__((aligned(16))) unsigned short As[128 * 32];
    __shared__ __attribute__((aligned(16))) unsigned short Bs[128 * 32];
    int e     = sched[blockIdx.y * 4 + 0];
    int m0    = sched[blockIdx.y * 4 + 1];
    int valid = sched[blockIdx.y * 4 + 2];
    if (valid == 0) return;
    int n0 = blockIdx.x * 128;

    int t = threadIdx.x;
    int lane = t & 63;
    int wave = t >> 6;
    int wm = wave >> 1, wn = wave & 1;
    int ln = lane & 15, q = lane >> 4;

    const unsigned short* wte = wt + (size_t)e * DIN * DOUT;

    f32x4 acc[4][4];
#pragma unroll
    for (int i = 0; i < 4; i++)
#pragma unroll
        for (int j = 0; j < 4; j++) acc[i][j] = (f32x4){0.f, 0.f, 0.f, 0.f};

    int c0 = t, c1 = t + 256;

    for (int k0 = 0; k0 < DIN; k0 += 32) {
        __syncthreads();
        {
            const unsigned short* ga0 = xb + (size_t)(m0 + (c0 >> 2)) * DIN + k0 + (c0 & 3) * 8;
            const unsigned short* ga1 = xb + (size_t)(m0 + (c1 >> 2)) * DIN + k0 + (c1 & 3) * 8;
            __builtin_amdgcn_global_load_lds((const g_void*)ga0, (lds_void*)((char*)As + wave * 1024), 16, 0, 0);
            __builtin_amdgcn_global_load_lds((const g_void*)ga1, (lds_void*)((char*)As + 4096 + wave * 1024), 16, 0, 0);
            const unsigned short* gb0 = wte + (size_t)(n0 + (c0 >> 2)) * DIN + k0 + (c0 & 3) * 8;
            const unsigned short* gb1 = wte + (size_t)(n0 + (c1 >> 2)) * DIN + k0 + (c1 & 3) * 8;
            __builtin_amdgcn_global_load_lds((const g_void*)gb0, (lds_void*)((char*)Bs + wave * 1024), 16, 0, 0);
            __builtin_amdgcn_global_load_lds((const g_void*)gb1, (lds_void*)((char*)Bs + 4096 + wave * 1024), 16, 0, 0);
        }
        __syncthreads();
        bf16x8 af[4], bfr[4];
#pragma unroll
        for (int mi = 0; mi < 4; mi++)
            af[mi] = *(const bf16x8*)((const char*)As + ((wm * 64 + mi * 16 + ln) * 64 + q * 16));
#pragma unroll
        for (int ni = 0; ni < 4; ni++)
            bfr[ni] = *(const bf16x8*)((const char*)Bs + ((wn * 64 + ni * 16 + ln) * 64 + q * 16));
#pragma unroll
        for (int mi = 0; mi < 4; mi++)
#pragma unroll
            for (int ni = 0; ni < 4; ni++)
                acc[mi][ni] = __builtin_amdgcn_mfma_f32_16x16x32_bf16(af[mi], bfr[ni], acc[mi][ni], 0, 0, 0);
    }

#pragma unroll
    for (int mi = 0; mi < 4; mi++) {
#pragma unroll
        for (int r = 0; r < 4; r++) {
            int row_l = wm * 64 + mi * 16 + q * 4 + r;
            if (row_l < valid) {
                float* orow = out + (size_t)(m0 + row_l) * DOUT + n0 + wn * 64 + ln;
#pragma unroll
                for (int ni = 0; ni < 4; ni++)
                    orow[ni * 16] = acc[mi][ni][r];
            }
        }
    }
}

// ================= lora pass1: inter = gather(xb, perm) @ Agt[g]^T, 64-row tiles =========
__global__ __launch_bounds__(256) void k_pass1(const unsigned short* __restrict__ xb,
                                               const unsigned short* __restrict__ Agt,
                                               const int* __restrict__ sched2,
                                               const int* __restrict__ perm,
                                               float* __restrict__ inter) {
    __shared__ __attribute__((aligned(16))) unsigned short As[64 * 32]; // 4 KB
    int g     = sched2[blockIdx.x * 4 + 0];
    int m0    = sched2[blockIdx.x * 4 + 1];
    int valid = sched2[blockIdx.x * 4 + 2];
    if (valid == 0) return;

    int t = threadIdx.x;
    int lane = t & 63, w = t >> 6;
    int ln = lane & 15, q = lane >> 4;

    const unsigned short* Ag = Agt + (size_t)g * RANK * DIN;
    int prow = perm[m0 + (t >> 2)];
    const unsigned short* ga_base = xb + (size_t)prow * DIN + (t & 3) * 8;

    f32x4 acc = (f32x4){0.f, 0.f, 0.f, 0.f};

    for (int k0 = 0; k0 < DIN; k0 += 32) {
        __syncthreads();
        __builtin_amdgcn_global_load_lds((const g_void*)(ga_base + k0),
                                         (lds_void*)((char*)As + w * 1024), 16, 0, 0);
        __syncthreads();
        bf16x8 bfr = *(const bf16x8*)(Ag + ln * DIN + k0 + q * 8);
        bf16x8 af  = *(const bf16x8*)((const char*)As + ((w * 16 + ln) * 64 + q * 16));
        acc = __builtin_amdgcn_mfma_f32_16x16x32_bf16(af, bfr, acc, 0, 0, 0);
    }
#pragma unroll
    for (int r = 0; r < 4; r++) {
        int row = w * 16 + q * 4 + r;
        if (row < valid)
            inter[(size_t)(m0 + row) * RANK + ln] = acc[r];
    }
}

// ================= lora pass2: out[perm[t]] += s * inter[t] @ lB[g], 64-row tiles ========
__global__ __launch_bounds__(256) void k_pass2(const float* __restrict__ inter,
                                               const int* __restrict__ sched2,
                                               const int* __restrict__ perm,
                                               const int* __restrict__ aidx,
                                               const float* __restrict__ lB,
                                               const float* __restrict__ scal,
                                               float* __restrict__ out) {
    __shared__ float Bsm[RANK * 256];   // 16 KB
    __shared__ float ism[TILE2 * RANK]; // 4 KB
    __shared__ float ssm[TILE2];
    __shared__ int   ptm[TILE2];
    int g     = sched2[blockIdx.x * 4 + 0];
    int m0    = sched2[blockIdx.x * 4 + 1];
    int valid = sched2[blockIdx.x * 4 + 2];
    if (valid == 0) return;
    int n0 = blockIdx.y * 256;
    int a = g & 7, e = g >> 3;
    int t = threadIdx.x;

    // stage B chunk: [16][256] fp32
    {
        const float* Bsrc = lB + ((size_t)(a * NEXP + e) * RANK + (t >> 4)) * DOUT + n0 + (t & 15) * 16;
        float* Bdst = &Bsm[(t >> 4) * 256 + (t & 15) * 16];
#pragma unroll
        for (int j = 0; j < 4; j++)
            *(float4*)(Bdst + j * 4) = *(const float4*)(Bsrc + j * 4);
    }
    // stage inter rows + perm + scale
    {
        int tok = t >> 2, part = t & 3;
        int p = (tok < valid) ? perm[m0 + tok] : 0;
        if (part == 0) {
            ptm[tok] = p;
            ssm[tok] = (tok < valid) ? scal[aidx[p]] : 0.f;
        }
        int srow = (tok < valid) ? (m0 + tok) : m0;
        *(float4*)&ism[tok * RANK + part * 4] = *(const float4*)(inter + (size_t)srow * RANK + part * 4);
    }
    __syncthreads();

    int lane = t & 63, w = t >> 6;
#pragma unroll 1
    for (int tk = 0; tk < 16; tk++) {
        int tok = w * 16 + tk;
        if (tok >= valid) continue;
        float s = ssm[tok];
        const float* ir = &ism[tok * RANK];
        float* orow = out + (size_t)ptm[tok] * DOUT + n0 + lane;
#pragma unroll
        for (int c = 0; c < 4; c++) {
            const float* bcol = &Bsm[lane + c * 64];
            float v = 0.f;
#pragma unroll
            for (int r = 0; r < RANK; r++)
                v += ir[r] * bcol[r * 256];
            orow[c * 64] += s * v;
        }
    }
}

extern "C" void kernel_launch(void* const* d_in, const int* in_sizes, int n_in,
                              void* d_out, int out_size, void* d_ws, size_t ws_size,
                              hipStream_t stream) {
    (void)in_sizes; (void)n_in; (void)out_size; (void)ws_size;
    const float* x    = (const float*)d_in[0];
    const int*   gs   = (const int*)d_in[1];
    const int*   aidx = (const int*)d_in[2];
    const float* W    = (const float*)d_in[3];
    const float* lA   = (const float*)d_in[4];
    const float* lB   = (const float*)d_in[5];
    const float* scal = (const float*)d_in[6];
    float* out = (float*)d_out;

    // ws layout (all 16B-aligned)
    char* ws = (char*)d_ws;
    unsigned short* xb    = (unsigned short*)ws;            size_t o = 33816576; // (T+128)*1024*2
    unsigned short* wt    = (unsigned short*)(ws + o);      o += 16777216;       // E*IN*OUT*2
    unsigned short* Agt   = (unsigned short*)(ws + o);      o += 2097152;        // 64*16*1024*2
    float*          inter = (float*)(ws + o);               o += 1048576;        // T*16*4
    int*            sched = (int*)(ws + o);                 o += 2176;           // 135*16
    int*            sched2= (int*)(ws + o);                 o += 5120;           // 320*16
    int*            gid   = (int*)(ws + o);                 o += 65536;          // T*4
    int*            perm  = (int*)(ws + o);                 o += 66048;          // (T+128)*4

    k_convert_all<<<NBX + NBW + NGRP, 256, 0, stream>>>(x, W, lA, xb, wt, Agt);
    k_route_all<<<1, 1024, 0, stream>>>(gs, aidx, gid, perm, sched, sched2);
    k_gemm<<<dim3(8, MAXTILES), 256, 0, stream>>>(xb, wt, sched, out);
    k_pass1<<<MAXT2, 256, 0, stream>>>(xb, Agt, sched2, perm, inter);
    k_pass2<<<dim3(MAXT2, 4), 256, 0, stream>>>(inter, sched2, perm, aidx, lB, scal, out);
}

// Round 4
// 294.682 us; speedup vs baseline: 1.9506x; 1.0817x over previous
//
#include <hip/hip_runtime.h>

// Problem constants (LoRAExpert)
#define T_TOK 16384
#define NEXP 8
#define DIN 1024
#define DOUT 1024
#define NADP 8
#define RANK 16
#define NGRP 64        // E*A groups
#define MAXTILES 135   // base gemm: 128 full + up to E-1 remainders (128-row tiles)
#define TILE2 64       // lora pass1 tiles: 64 rows
#define MAXT2 320      // 256 full + up to NGRP remainders
#define BK 64          // base gemm K-tile

typedef float f32x4 __attribute__((ext_vector_type(4)));
typedef __bf16 bf16x8 __attribute__((ext_vector_type(8)));

typedef __attribute__((address_space(3))) void lds_void;
typedef __attribute__((address_space(1))) void g_void;

static __device__ __forceinline__ unsigned short f2bf(float f) {
    union { float f; unsigned u; } c; c.f = f;
    unsigned r = c.u + 0x7FFFu + ((c.u >> 16) & 1u);
    return (unsigned short)(r >> 16);
}

// ================= fused converts =================
// [0,NBX): x->bf16 ; [NBX,NBX+NBW): W->Wt ; then NGRP blocks lora_A->Agt ; then 64 blocks lB->Blt
#define NBX 16512
#define NBW 2048
__global__ __launch_bounds__(256) void k_convert_all(const float* __restrict__ x,
                                                     const float* __restrict__ W,
                                                     const float* __restrict__ lA,
                                                     const float* __restrict__ lB,
                                                     unsigned short* __restrict__ xb,
                                                     unsigned short* __restrict__ Wt,
                                                     unsigned short* __restrict__ Agt,
                                                     unsigned short* __restrict__ Blt) {
    __shared__ __attribute__((aligned(16))) unsigned short lds_u[16 * 1032]; // 33 KB union
    int b = blockIdx.x;
    int t = threadIdx.x;
    if (b < NBX) {
        // ---- convert x, zero-pad 128 extra rows ----
        size_t i = ((size_t)b * 256 + t) * 4;
        ushort4 u;
        if (i < (size_t)T_TOK * DIN) {
            float4 v = *(const float4*)(x + i);
            u.x = f2bf(v.x); u.y = f2bf(v.y); u.z = f2bf(v.z); u.w = f2bf(v.w);
        } else {
            u.x = 0; u.y = 0; u.z = 0; u.w = 0;
        }
        *(ushort4*)(xb + i) = u;
    } else if (b < NBX + NBW) {
        // ---- convert+transpose W [E][IN][OUT] -> [E][OUT][IN] ----
        int idx = b - NBX;
        int e = idx >> 8;
        int k0 = ((idx >> 4) & 15) * 64, n0 = (idx & 15) * 64;
        const float* We = W + (size_t)e * DIN * DOUT;
        unsigned short* Wte = Wt + (size_t)e * DIN * DOUT;
        int kr = t >> 2;
        int nc = (t & 3) * 16;
#pragma unroll
        for (int j = 0; j < 4; j++) {
            float4 v = *(const float4*)(We + (size_t)(k0 + kr) * DOUT + n0 + nc + j * 4);
            lds_u[(nc + j * 4 + 0) * 80 + kr] = f2bf(v.x);
            lds_u[(nc + j * 4 + 1) * 80 + kr] = f2bf(v.y);
            lds_u[(nc + j * 4 + 2) * 80 + kr] = f2bf(v.z);
            lds_u[(nc + j * 4 + 3) * 80 + kr] = f2bf(v.w);
        }
        __syncthreads();
        int n = t >> 2;
        int kk = (t & 3) * 16;
        uint4 v0 = *(const uint4*)&lds_u[n * 80 + kk];
        uint4 v1 = *(const uint4*)&lds_u[n * 80 + kk + 8];
        *(uint4*)(Wte + (size_t)(n0 + n) * DIN + k0 + kk) = v0;
        *(uint4*)(Wte + (size_t)(n0 + n) * DIN + k0 + kk + 8) = v1;
    } else if (b < NBX + NBW + NGRP) {
        // ---- convert+transpose lora_A [A][E][K][R] -> Agt [g=e*8+a][R][K] ----
        int g = b - (NBX + NBW);
        int a = g & 7, e = g >> 3;
        const float* src = lA + (size_t)(a * NEXP + e) * DIN * RANK;
#pragma unroll
        for (int it = 0; it < 4; it++) {
            int k = it * 256 + t;
            const float4* p = (const float4*)(src + (size_t)k * RANK);
            float4 v0 = p[0], v1 = p[1], v2 = p[2], v3 = p[3];
            lds_u[0 * 1032 + k] = f2bf(v0.x);  lds_u[1 * 1032 + k] = f2bf(v0.y);
            lds_u[2 * 1032 + k] = f2bf(v0.z);  lds_u[3 * 1032 + k] = f2bf(v0.w);
            lds_u[4 * 1032 + k] = f2bf(v1.x);  lds_u[5 * 1032 + k] = f2bf(v1.y);
            lds_u[6 * 1032 + k] = f2bf(v1.z);  lds_u[7 * 1032 + k] = f2bf(v1.w);
            lds_u[8 * 1032 + k] = f2bf(v2.x);  lds_u[9 * 1032 + k] = f2bf(v2.y);
            lds_u[10 * 1032 + k] = f2bf(v2.z); lds_u[11 * 1032 + k] = f2bf(v2.w);
            lds_u[12 * 1032 + k] = f2bf(v3.x); lds_u[13 * 1032 + k] = f2bf(v3.y);
            lds_u[14 * 1032 + k] = f2bf(v3.z); lds_u[15 * 1032 + k] = f2bf(v3.w);
        }
        __syncthreads();
        unsigned short* dst = Agt + (size_t)g * RANK * DIN;
        int r = t >> 4, ks = (t & 15) * 64;
#pragma unroll
        for (int j = 0; j < 8; j++)
            *(uint4*)(dst + r * DIN + ks + j * 8) = *(const uint4*)&lds_u[r * 1032 + ks + j * 8];
    } else {
        // ---- lB [A][E][R][N] fp32 -> Blt [E][N][A*16+R] bf16 (B^T operand for lora MFMA) ----
        int idx = b - (NBX + NBW + NGRP);
        int e = idx >> 3, nc = idx & 7;           // n chunk of 128
        // load: tile[k=a*16+r][n_local] with row pitch 129
        int k = t >> 1, half = t & 1;
        int a = k >> 4, r = k & 15;
        const float* src = lB + ((size_t)(a * NEXP + e) * RANK + r) * DOUT + nc * 128 + half * 64;
#pragma unroll
        for (int j = 0; j < 16; j++) {
            float4 v = *(const float4*)(src + j * 4);
            int nl = half * 64 + j * 4;
            lds_u[k * 129 + nl + 0] = f2bf(v.x);
            lds_u[k * 129 + nl + 1] = f2bf(v.y);
            lds_u[k * 129 + nl + 2] = f2bf(v.z);
            lds_u[k * 129 + nl + 3] = f2bf(v.w);
        }
        __syncthreads();
        // store: row n -> 128 contiguous k
        int nl = t >> 1, kh = t & 1;
        unsigned short* dst = Blt + ((size_t)(e * 1024 + nc * 128 + nl)) * 128 + kh * 64;
#pragma unroll
        for (int g2 = 0; g2 < 8; g2++) {
            uint4 pv;
            unsigned short s0 = lds_u[(kh * 64 + g2 * 8 + 0) * 129 + nl];
            unsigned short s1 = lds_u[(kh * 64 + g2 * 8 + 1) * 129 + nl];
            unsigned short s2 = lds_u[(kh * 64 + g2 * 8 + 2) * 129 + nl];
            unsigned short s3 = lds_u[(kh * 64 + g2 * 8 + 3) * 129 + nl];
            unsigned short s4 = lds_u[(kh * 64 + g2 * 8 + 4) * 129 + nl];
            unsigned short s5 = lds_u[(kh * 64 + g2 * 8 + 5) * 129 + nl];
            unsigned short s6 = lds_u[(kh * 64 + g2 * 8 + 6) * 129 + nl];
            unsigned short s7 = lds_u[(kh * 64 + g2 * 8 + 7) * 129 + nl];
            pv.x = (unsigned)s0 | ((unsigned)s1 << 16);
            pv.y = (unsigned)s2 | ((unsigned)s3 << 16);
            pv.z = (unsigned)s4 | ((unsigned)s5 << 16);
            pv.w = (unsigned)s6 | ((unsigned)s7 << 16);
            *(uint4*)(dst + g2 * 8) = pv;
        }
    }
}

// ================= fused routing: hist + scan + schedules + scatter (one block) ==========
__global__ __launch_bounds__(1024) void k_route_all(const int* __restrict__ gs,
                                                    const int* __restrict__ aidx,
                                                    int* __restrict__ gid,
                                                    int* __restrict__ perm,
                                                    int* __restrict__ sched,
                                                    int* __restrict__ sched2) {
    __shared__ int hist[NGRP];
    __shared__ int cursor[NGRP];
    __shared__ int ebase[NEXP + 1];
    int t = threadIdx.x;
    if (t < NGRP) hist[t] = 0;
    if (t == 0) {
        int acc = 0;
        for (int i = 0; i < NEXP; i++) { ebase[i] = acc; acc += gs[i]; }
        ebase[NEXP] = acc;
    }
    __syncthreads();
    for (int i = 0; i < T_TOK / 1024; i++) {
        int tok = i * 1024 + t;
        int e = 0;
#pragma unroll
        for (int j = 1; j < NEXP; j++) e += (tok >= ebase[j]);
        int g = e * NADP + aidx[tok];
        gid[tok] = g;
        atomicAdd(&hist[g], 1);
    }
    if (t < 128) perm[T_TOK + t] = T_TOK;  // pad: overruns gather zero row of xb
    __syncthreads();
    if (t == 0) {
        int off = 0, tc = 0;
        for (int g = 0; g < NGRP; g++) {
            cursor[g] = off;
            int sz = hist[g];
            for (int m = 0; m < sz; m += TILE2) {
                sched2[tc * 4 + 0] = g;
                sched2[tc * 4 + 1] = off + m;
                sched2[tc * 4 + 2] = (sz - m) < TILE2 ? (sz - m) : TILE2;
                sched2[tc * 4 + 3] = 0;
                tc++;
            }
            off += sz;
        }
        for (; tc < MAXT2; tc++) {
            sched2[tc * 4 + 0] = 0; sched2[tc * 4 + 1] = 0;
            sched2[tc * 4 + 2] = 0; sched2[tc * 4 + 3] = 0;
        }
    } else if (t == 64) {
        int off = 0, tc = 0;
        for (int e = 0; e < NEXP; e++) {
            int sz = ebase[e + 1] - ebase[e];
            for (int m = 0; m < sz; m += 128) {
                sched[tc * 4 + 0] = e;
                sched[tc * 4 + 1] = off + m;
                sched[tc * 4 + 2] = (sz - m) < 128 ? (sz - m) : 128;
                sched[tc * 4 + 3] = 0;
                tc++;
            }
            off += sz;
        }
        for (; tc < MAXTILES; tc++) {
            sched[tc * 4 + 0] = 0; sched[tc * 4 + 1] = 0;
            sched[tc * 4 + 2] = 0; sched[tc * 4 + 3] = 0;
        }
    }
    __syncthreads();
    for (int i = 0; i < T_TOK / 1024; i++) {
        int tok = i * 1024 + t;
        int pos = atomicAdd(&cursor[gid[tok]], 1);
        perm[pos] = tok;
    }
}

// ================= lora pass1: inter[orig_tok] = (x @ lora_A[g])  (scatter by perm) ======
__global__ __launch_bounds__(256) void k_pass1(const unsigned short* __restrict__ xb,
                                               const unsigned short* __restrict__ Agt,
                                               const int* __restrict__ sched2,
                                               const int* __restrict__ perm,
                                               float* __restrict__ inter) {
    __shared__ __attribute__((aligned(16))) unsigned short As[64 * 32]; // 4 KB
    int g     = sched2[blockIdx.x * 4 + 0];
    int m0    = sched2[blockIdx.x * 4 + 1];
    int valid = sched2[blockIdx.x * 4 + 2];
    if (valid == 0) return;

    int t = threadIdx.x;
    int lane = t & 63, w = t >> 6;
    int ln = lane & 15, q = lane >> 4;

    const unsigned short* Ag = Agt + (size_t)g * RANK * DIN;
    int prow = perm[m0 + (t >> 2)];
    const unsigned short* ga_base = xb + (size_t)prow * DIN + (t & 3) * 8;

    f32x4 acc = (f32x4){0.f, 0.f, 0.f, 0.f};

    for (int k0 = 0; k0 < DIN; k0 += 32) {
        __syncthreads();
        __builtin_amdgcn_global_load_lds((const g_void*)(ga_base + k0),
                                         (lds_void*)((char*)As + w * 1024), 16, 0, 0);
        __syncthreads();
        bf16x8 bfr = *(const bf16x8*)(Ag + ln * DIN + k0 + q * 8);
        bf16x8 af  = *(const bf16x8*)((const char*)As + ((w * 16 + ln) * 64 + q * 16));
        acc = __builtin_amdgcn_mfma_f32_16x16x32_bf16(af, bfr, acc, 0, 0, 0);
    }
#pragma unroll
    for (int r = 0; r < 4; r++) {
        int row = w * 16 + q * 4 + r;
        if (row < valid) {
            int ptok = perm[m0 + row];
            inter[(size_t)ptok * RANK + ln] = acc[r];
        }
    }
}

// ================= base grouped GEMM + fused LoRA-B, bf16 MFMA, 128x128xBK ===============
// grid = dim3(8, MAXTILES): n0 fastest so consecutive blocks share the A tile
__global__ __launch_bounds__(256) void k_gemm(const unsigned short* __restrict__ xb,
                                              const unsigned short* __restrict__ wt,
                                              const int* __restrict__ sched,
                                              const float* __restrict__ inter,
                                              const int* __restrict__ aidx,
                                              const float* __restrict__ scal,
                                              const unsigned short* __restrict__ Blt,
                                              float* __restrict__ out) {
    __shared__ __attribute__((aligned(16))) unsigned short smem[128 * 128]; // 32 KB
    unsigned short* As = smem;          // [128][64] xor-swizzled
    unsigned short* Bs = smem + 8192;   // [128][64] xor-swizzled
    int e     = sched[blockIdx.y * 4 + 0];
    int m0    = sched[blockIdx.y * 4 + 1];
    int valid = sched[blockIdx.y * 4 + 2];
    if (valid == 0) return;
    int n0 = blockIdx.x * 128;

    int t = threadIdx.x;
    int lane = t & 63;
    int wave = t >> 6;
    int wm = wave >> 1, wn = wave & 1;
    int ln = lane & 15, q = lane >> 4;

    const unsigned short* wte = wt + (size_t)e * DIN * DOUT;

    f32x4 acc[4][4];
#pragma unroll
    for (int i = 0; i < 4; i++)
#pragma unroll
        for (int j = 0; j < 4; j++) acc[i][j] = (f32x4){0.f, 0.f, 0.f, 0.f};

    // staging: lane loads global chunk g = (lane&7)^(row&7) so physical LDS slot lane&7
    // holds swizzled content; LDS dest = wave-uniform base + lane*16 (HW constraint).
    int srow[4], skoff[4];
#pragma unroll
    for (int j = 0; j < 4; j++) {
        srow[j]  = j * 32 + wave * 8 + (lane >> 3);
        skoff[j] = ((lane & 7) ^ (srow[j] & 7)) * 8;
    }

    for (int k0 = 0; k0 < DIN; k0 += BK) {
        __syncthreads();
#pragma unroll
        for (int j = 0; j < 4; j++) {
            __builtin_amdgcn_global_load_lds(
                (const g_void*)(xb + (size_t)(m0 + srow[j]) * DIN + k0 + skoff[j]),
                (lds_void*)((char*)As + j * 4096 + wave * 1024), 16, 0, 0);
            __builtin_amdgcn_global_load_lds(
                (const g_void*)(wte + (size_t)(n0 + srow[j]) * DIN + k0 + skoff[j]),
                (lds_void*)((char*)Bs + j * 4096 + wave * 1024), 16, 0, 0);
        }
        __syncthreads();
#pragma unroll
        for (int kf = 0; kf < 2; kf++) {
            bf16x8 af[4], bfr[4];
#pragma unroll
            for (int mi = 0; mi < 4; mi++) {
                int row = wm * 64 + mi * 16 + ln;
                int slot = (kf * 4 + q) ^ (ln & 7);      // row&7 == ln&7
                af[mi] = *(const bf16x8*)((const char*)As + row * 128 + slot * 16);
            }
#pragma unroll
            for (int ni = 0; ni < 4; ni++) {
                int row = wn * 64 + ni * 16 + ln;
                int slot = (kf * 4 + q) ^ (ln & 7);
                bfr[ni] = *(const bf16x8*)((const char*)Bs + row * 128 + slot * 16);
            }
#pragma unroll
            for (int mi = 0; mi < 4; mi++)
#pragma unroll
                for (int ni = 0; ni < 4; ni++)
                    acc[mi][ni] = __builtin_amdgcn_mfma_f32_16x16x32_bf16(af[mi], bfr[ni], acc[mi][ni], 0, 0, 0);
        }
    }

    // ---- fused LoRA: acc += P @ Blt[e][n0 slab], P[row][a*16+r] = s_a * inter[row][r] ----
    __syncthreads();
    // zero P (entire 32 KB smem)
    {
        uint4 z = {0u, 0u, 0u, 0u};
#pragma unroll
        for (int j = 0; j < 8; j++)
            *(uint4*)((char*)smem + (j * 256 + t) * 16) = z;
    }
    __syncthreads();
    {
        int row = t >> 1, h = t & 1;
        if (row < valid) {
            int tok = m0 + row;
            int a = aidx[tok];
            float s = scal[a];
            const float* ip = inter + (size_t)tok * RANK + h * 8;
            float4 v0 = *(const float4*)ip;
            float4 v1 = *(const float4*)(ip + 4);
            unsigned short u[8];
            u[0] = f2bf(s * v0.x); u[1] = f2bf(s * v0.y); u[2] = f2bf(s * v0.z); u[3] = f2bf(s * v0.w);
            u[4] = f2bf(s * v1.x); u[5] = f2bf(s * v1.y); u[6] = f2bf(s * v1.z); u[7] = f2bf(s * v1.w);
            int slot = (a * 2 + h) ^ (row & 15);         // 16-slot xor swizzle
            *(uint4*)((char*)smem + row * 256 + slot * 16) = *(uint4*)u;
        }
    }
    __syncthreads();
#pragma unroll
    for (int kf = 0; kf < 4; kf++) {
        bf16x8 af[4], bfr[4];
        const unsigned short* bbase = Blt + ((size_t)(e * 1024 + n0 + wn * 64 + ln)) * 128 + kf * 32 + q * 8;
#pragma unroll
        for (int ni = 0; ni < 4; ni++)
            bfr[ni] = *(const bf16x8*)(bbase + (size_t)ni * 16 * 128);
#pragma unroll
        for (int mi = 0; mi < 4; mi++) {
            int row = wm * 64 + mi * 16 + ln;
            int slot = (kf * 4 + q) ^ ln;                // row&15 == ln
            af[mi] = *(const bf16x8*)((const char*)smem + row * 256 + slot * 16);
        }
#pragma unroll
        for (int mi = 0; mi < 4; mi++)
#pragma unroll
            for (int ni = 0; ni < 4; ni++)
                acc[mi][ni] = __builtin_amdgcn_mfma_f32_16x16x32_bf16(af[mi], bfr[ni], acc[mi][ni], 0, 0, 0);
    }

    // ---- store (single writer of out) ----
#pragma unroll
    for (int mi = 0; mi < 4; mi++) {
#pragma unroll
        for (int r = 0; r < 4; r++) {
            int row_l = wm * 64 + mi * 16 + q * 4 + r;
            if (row_l < valid) {
                float* orow = out + (size_t)(m0 + row_l) * DOUT + n0 + wn * 64 + ln;
#pragma unroll
                for (int ni = 0; ni < 4; ni++)
                    orow[ni * 16] = acc[mi][ni][r];
            }
        }
    }
}

extern "C" void kernel_launch(void* const* d_in, const int* in_sizes, int n_in,
                              void* d_out, int out_size, void* d_ws, size_t ws_size,
                              hipStream_t stream) {
    (void)in_sizes; (void)n_in; (void)out_size; (void)ws_size;
    const float* x    = (const float*)d_in[0];
    const int*   gs   = (const int*)d_in[1];
    const int*   aidx = (const int*)d_in[2];
    const float* W    = (const float*)d_in[3];
    const float* lA   = (const float*)d_in[4];
    const float* lB   = (const float*)d_in[5];
    const float* scal = (const float*)d_in[6];
    float* out = (float*)d_out;

    // ws layout (16B-aligned)
    char* ws = (char*)d_ws;
    unsigned short* xb    = (unsigned short*)ws;            size_t o = 33816576; // (T+128)*1024*2
    unsigned short* wt    = (unsigned short*)(ws + o);      o += 16777216;       // E*IN*OUT*2
    unsigned short* Agt   = (unsigned short*)(ws + o);      o += 2097152;        // 64*16*1024*2
    unsigned short* Blt   = (unsigned short*)(ws + o);      o += 2097152;        // 8*1024*128*2
    float*          inter = (float*)(ws + o);               o += 1048576;        // T*16*4
    int*            sched = (int*)(ws + o);                 o += 2176;           // 135*16
    int*            sched2= (int*)(ws + o);                 o += 5120;           // 320*16
    int*            gid   = (int*)(ws + o);                 o += 65536;          // T*4
    int*            perm  = (int*)(ws + o);                 o += 66048;          // (T+128)*4

    k_convert_all<<<NBX + NBW + NGRP + 64, 256, 0, stream>>>(x, W, lA, lB, xb, wt, Agt, Blt);
    k_route_all<<<1, 1024, 0, stream>>>(gs, aidx, gid, perm, sched, sched2);
    k_pass1<<<MAXT2, 256, 0, stream>>>(xb, Agt, sched2, perm, inter);
    k_gemm<<<dim3(8, MAXTILES), 256, 0, stream>>>(xb, wt, sched, inter, aidx, scal, Blt, out);
}